// Round 7
// baseline (76.593 us; speedup 1.0000x reference)
//
#include <hip/hip_runtime.h>
#include <stdint.h>

typedef _Float16 f16x8 __attribute__((ext_vector_type(8)));
typedef __fp16 fp16x2 __attribute__((ext_vector_type(2)));
typedef float f32x4 __attribute__((ext_vector_type(4)));

#define BC (16384 * 256)

__device__ __forceinline__ f16x8 cvt8(f32x4 a, f32x4 b) {
  fp16x2 p0 = __builtin_amdgcn_cvt_pkrtz(a[0], a[1]);
  fp16x2 p1 = __builtin_amdgcn_cvt_pkrtz(a[2], a[3]);
  fp16x2 p2 = __builtin_amdgcn_cvt_pkrtz(b[0], b[1]);
  fp16x2 p3 = __builtin_amdgcn_cvt_pkrtz(b[2], b[3]);
  f16x8 o;
  o[0] = (_Float16)p0[0]; o[1] = (_Float16)p0[1];
  o[2] = (_Float16)p1[0]; o[3] = (_Float16)p1[1];
  o[4] = (_Float16)p2[0]; o[5] = (_Float16)p2[1];
  o[6] = (_Float16)p3[0]; o[7] = (_Float16)p3[1];
  return o;
}

__device__ __forceinline__ float tanh_fast(float v) {
  float a = fminf(fabsf(v), 18.f);
  float t = __expf(2.f * a);
  float r = (t - 1.f) * __builtin_amdgcn_rcpf(t + 1.f);
  return copysignf(r, v);
}

// ===================== streaming path (preferred) =====================

// Fragment-major weights (R4 layout, verified):
// wsB[(((kc*8 + w)*8 + f)*64 + l15*4 + lg)*8 + b] = W_s[c][k],
//   f = g*4 + s, c = w*32 + g*16 + l15, k = kc*32 + lg*8 + b.
// Wave frag load = contiguous 1 KB. s=0 is Wu (K >= 256 zero-padded).
__global__ __launch_bounds__(256) void pack_w_frag(const float* __restrict__ Wu,
                                                   const float* __restrict__ Wg,
                                                   const float* __restrict__ Wa,
                                                   const float* __restrict__ Wd,
                                                   _Float16* __restrict__ wsB) {
  int tid = blockIdx.x * 256 + threadIdx.x;  // 65536 total
  int lg = tid & 3;
  int l15 = (tid >> 2) & 15;
  int f = (tid >> 6) & 7;
  int w = (tid >> 9) & 7;
  int kc = tid >> 12;
  int s = f & 3;
  int g = f >> 2;
  int c = w * 32 + g * 16 + l15;
  int k0 = kc * 32 + lg * 8;
  float v[8];
  if (s == 0) {
    if (k0 < 256) {
      const float* p = Wu + (size_t)c * 256 + k0;
#pragma unroll
      for (int i = 0; i < 8; ++i) v[i] = p[i];
    } else {
#pragma unroll
      for (int i = 0; i < 8; ++i) v[i] = 0.f;
    }
  } else {
    const float* p = (s == 1 ? Wg : (s == 2 ? Wa : Wd)) + (size_t)c * 512 + k0;
#pragma unroll
    for (int i = 0; i < 8; ++i) v[i] = p[i];
  }
  f32x4 a = {v[0], v[1], v[2], v[3]};
  f32x4 b = {v[4], v[5], v[6], v[7]};
  *reinterpret_cast<f16x8*>(wsB + (size_t)tid * 8) = cvt8(a, b);
}

// Pre-pack A = [x | h] f32 -> f16, MFMA-fragment-major:
// wsA[((row16*16 + kc)*64 + lg*16 + l15)*8 + b] = xh[row16*16 + l15][kc*32 + lg*8 + b]
// (kc<8 from x, kc>=8 from h). Wave frag load in main = contiguous 1 KB.
__global__ __launch_bounds__(256) void pack_a(const float* __restrict__ x,
                                              const float* __restrict__ h,
                                              _Float16* __restrict__ wsA) {
  int tid = blockIdx.x * 256 + threadIdx.x;  // 1,048,576 total
  int l15 = tid & 15;
  int lg = (tid >> 4) & 3;
  int kc = (tid >> 6) & 15;
  int row16 = tid >> 10;
  int row = row16 * 16 + l15;
  const float* src = (kc < 8)
      ? (x + (size_t)row * 256 + kc * 32 + lg * 8)
      : (h + (size_t)row * 256 + (kc - 8) * 32 + lg * 8);
  f32x4 a = *reinterpret_cast<const f32x4*>(src);
  f32x4 b = *reinterpret_cast<const f32x4*>(src + 4);
  *reinterpret_cast<f16x8*>(wsA + (size_t)tid * 8) = cvt8(a, b);
}

// Zero-LDS zero-barrier fused GEMM + epilogue. All operands fragment-major:
// every load is a contiguous 1 KB wave-load. Wave tile 32 rows x 32 c x 4 strips.
// 4 waves/block share one cb -> B frags L1-resident.
__global__ __launch_bounds__(256, 4) void rwa_stream(
    const float* __restrict__ nt_, const float* __restrict__ dt_,
    const float* __restrict__ amax_, const float* __restrict__ bu,
    const float* __restrict__ bg, const _Float16* __restrict__ wsA,
    const _Float16* __restrict__ wsB, float* __restrict__ out) {
  const int tid = threadIdx.x;
  const int lane = tid & 63;
  const int l15 = lane & 15;
  const int lg = lane >> 4;
  const int wv = tid >> 6;
  const int bid = blockIdx.x;
  const int cb = bid & 7;                 // all 4 waves: same cb (B L1 reuse)
  const int w32 = (bid >> 3) * 4 + wv;    // 0..511, 32-row stripe
  const int row0 = w32 * 32;

  const _Float16* aa = wsA + (size_t)(w32 * 2) * 8192 + (size_t)lane * 8;
  const _Float16* bb = wsB + (size_t)cb * 4096 + (size_t)(l15 * 4 + lg) * 8;

  f32x4 acc[2][2][4] = {};  // [mi][g][s]

#pragma unroll
  for (int kc = 0; kc < 16; ++kc) {
    f16x8 af0 = *reinterpret_cast<const f16x8*>(aa + kc * 512);
    f16x8 af1 = *reinterpret_cast<const f16x8*>(aa + 8192 + kc * 512);
    const _Float16* bk = bb + (size_t)kc * 32768;
#pragma unroll
    for (int g = 0; g < 2; ++g) {
#pragma unroll
      for (int s = 0; s < 4; ++s) {
        if (s == 0 && kc >= 8) continue;  // Wu zero-pad: skip load+MFMA
        f16x8 bf = *reinterpret_cast<const f16x8*>(bk + (g * 4 + s) * 512);
        acc[0][g][s] =
            __builtin_amdgcn_mfma_f32_16x16x32_f16(af0, bf, acc[0][g][s], 0, 0, 0);
        acc[1][g][s] =
            __builtin_amdgcn_mfma_f32_16x16x32_f16(af1, bf, acc[1][g][s], 0, 0, 0);
      }
    }
  }

  // Epilogue: lane owns (r,c); u,g,a,dec local. C/D: col=l15, row=lg*4+rg (+mi*16).
#pragma unroll
  for (int g = 0; g < 2; ++g) {
    const int c = cb * 32 + g * 16 + l15;
    const float buv = bu[c];
    const float bgv = bg[c];
#pragma unroll
    for (int mi = 0; mi < 2; ++mi) {
#pragma unroll
      for (int rg = 0; rg < 4; ++rg) {
        const int r = row0 + mi * 16 + lg * 4 + rg;
        const int idx = r * 256 + c;
        const float u = acc[mi][g][0][rg] + buv;
        const float gt = acc[mi][g][1][rg] + bgv;
        const float a = acc[mi][g][2][rg];
        const float dr = acc[mi][g][3][rg];
        const float sig = __builtin_amdgcn_rcpf(1.f + __expf(-dr));
        const float z = u * tanh_fast(gt);
        const float am = amax_[idx];
        const float e_neg = __expf(-sig);
        const float a_new = fmaxf(am * e_neg, a);
        const float comm = __expf(am - a_new - sig);
        const float escal = __expf(a - a_new);
        const float n_new = nt_[idx] * comm + z * escal;
        const float d_new = dt_[idx] * comm + escal;
        const float h_new = tanh_fast(n_new * __builtin_amdgcn_rcpf(d_new));
        out[idx] = n_new;
        out[BC + idx] = d_new;
        out[2 * BC + idx] = h_new;
        out[3 * BC + idx] = a_new;
      }
    }
  }
}

// ===================== fallback path (R6, verified 52.6 us) =====================

__global__ __launch_bounds__(256) void pack_w_swz(const float* __restrict__ Wu,
                                                  const float* __restrict__ Wg,
                                                  const float* __restrict__ Wa,
                                                  const float* __restrict__ Wd,
                                                  _Float16* __restrict__ wsB) {
  int t = blockIdx.x * 256 + threadIdx.x;
  int slot = t & 7;
  int kt = (t >> 3) & 7;
  int row = (t >> 6) & 127;
  int cb = t >> 13;
  int strip = (row >> 4) & 3;
  int wn = row >> 6;
  int t16 = row & 15;
  int c = cb * 32 + wn * 16 + t16;
  int k0 = kt * 64 + (slot ^ (row & 7)) * 8;
  float v[8];
  if (strip == 0) {
    if (k0 < 256) {
      const float* p = Wu + (size_t)c * 256 + k0;
#pragma unroll
      for (int i = 0; i < 8; ++i) v[i] = p[i];
    } else {
#pragma unroll
      for (int i = 0; i < 8; ++i) v[i] = 0.f;
    }
  } else {
    const float* p = (strip == 1 ? Wg : (strip == 2 ? Wa : Wd)) + (size_t)c * 512 + k0;
#pragma unroll
    for (int i = 0; i < 8; ++i) v[i] = p[i];
  }
  f32x4 a = {v[0], v[1], v[2], v[3]};
  f32x4 b = {v[4], v[5], v[6], v[7]};
  *reinterpret_cast<f16x8*>(wsB + (size_t)cb * 65536 + row * 512 + kt * 64 + slot * 8) =
      cvt8(a, b);
}

__global__ __launch_bounds__(256, 6) void rwa_lds(
    const float* __restrict__ x, const float* __restrict__ nt_,
    const float* __restrict__ dt_, const float* __restrict__ h,
    const float* __restrict__ amax_, const float* __restrict__ bu,
    const float* __restrict__ bg, const _Float16* __restrict__ wsB,
    float* __restrict__ out) {
  __shared__ __align__(16) _Float16 ldsA[64 * 64];
  __shared__ __align__(16) _Float16 ldsB[128 * 64];

  const int tid = threadIdx.x;
  const int lane = tid & 63;
  const int l15 = lane & 15;
  const int lg = lane >> 4;
  const int wv = tid >> 6;
  const int wm = wv & 1;
  const int wn = wv >> 1;

  const int bid = blockIdx.x;
  const int xcd = bid & 7;
  const int q = bid >> 3;
  const int cb = q & 7;
  const int rowblk = xcd * 32 + (q >> 3);
  const int row0 = rowblk * 64;

  const int ar = tid >> 2;
  const int aq = tid & 3;

  const _Float16* bsrc0 = wsB + (size_t)cb * 65536 + (tid >> 3) * 512 + (tid & 7) * 8;

  f32x4 acc[2][4] = {};

  for (int kt = 0; kt < 8; ++kt) {
#pragma unroll
    for (int i = 0; i < 4; ++i) {
      __builtin_amdgcn_global_load_lds(
          (const __attribute__((address_space(1))) uint32_t*)(bsrc0 + i * 16384 + kt * 64),
          (__attribute__((address_space(3))) uint32_t*)(ldsB + wv * 512 + i * 2048),
          16, 0, 0);
    }
    {
      const float* asrc =
          (kt < 4 ? x : h) + (size_t)(row0 + ar) * 256 + (kt & 3) * 64 + aq * 16;
      f32x4 av[4];
#pragma unroll
      for (int i = 0; i < 4; ++i) av[i] = *reinterpret_cast<const f32x4*>(asrc + i * 4);
#pragma unroll
      for (int j = 0; j < 2; ++j) {
        f16x8 o = cvt8(av[2 * j], av[2 * j + 1]);
        const int slot = (aq * 2 + j) ^ (ar & 7);
        *reinterpret_cast<f16x8*>(reinterpret_cast<char*>(ldsA) + ar * 128 + slot * 16) = o;
      }
    }
    __syncthreads();

    const bool doU = (kt < 4);
    const int rswz = (l15 & 7) << 4;
#pragma unroll
    for (int ks = 0; ks < 2; ++ks) {
      f16x8 af[2], bf[4];
#pragma unroll
      for (int mi = 0; mi < 2; ++mi) {
        const int row = wm * 32 + mi * 16 + l15;
        af[mi] = *reinterpret_cast<const f16x8*>(
            reinterpret_cast<const char*>(ldsA) + row * 128 + ((ks * 64 + lg * 16) ^ rswz));
      }
#pragma unroll
      for (int s = 0; s < 4; ++s) {
        if (s == 0 && !doU) continue;
        const int row = wn * 64 + s * 16 + l15;
        bf[s] = *reinterpret_cast<const f16x8*>(
            reinterpret_cast<const char*>(ldsB) + row * 128 + ((ks * 64 + lg * 16) ^ rswz));
      }
#pragma unroll
      for (int s = 0; s < 4; ++s) {
        if (s == 0 && !doU) continue;
#pragma unroll
        for (int mi = 0; mi < 2; ++mi)
          acc[mi][s] = __builtin_amdgcn_mfma_f32_16x16x32_f16(af[mi], bf[s], acc[mi][s], 0, 0, 0);
      }
    }
    __syncthreads();
  }

  const int c = cb * 32 + wn * 16 + l15;
  const float buv = bu[c];
  const float bgv = bg[c];
#pragma unroll
  for (int mi = 0; mi < 2; ++mi) {
#pragma unroll
    for (int rg = 0; rg < 4; ++rg) {
      const int r = row0 + wm * 32 + mi * 16 + lg * 4 + rg;
      const int idx = r * 256 + c;
      const float u = acc[mi][0][rg] + buv;
      const float gt = acc[mi][1][rg] + bgv;
      const float a = acc[mi][2][rg];
      const float dr = acc[mi][3][rg];
      const float sig = __builtin_amdgcn_rcpf(1.f + __expf(-dr));
      const float z = u * tanh_fast(gt);
      const float am = amax_[idx];
      const float e_neg = __expf(-sig);
      const float a_new = fmaxf(am * e_neg, a);
      const float comm = __expf(am - a_new - sig);
      const float escal = __expf(a - a_new);
      const float n_new = nt_[idx] * comm + z * escal;
      const float d_new = dt_[idx] * comm + escal;
      const float h_new = tanh_fast(n_new * __builtin_amdgcn_rcpf(d_new));
      out[idx] = n_new;
      out[BC + idx] = d_new;
      out[2 * BC + idx] = h_new;
      out[3 * BC + idx] = a_new;
    }
  }
}

extern "C" void kernel_launch(void* const* d_in, const int* in_sizes, int n_in,
                              void* d_out, int out_size, void* d_ws, size_t ws_size,
                              hipStream_t stream) {
  const float* x_t    = (const float*)d_in[0];
  const float* n_t    = (const float*)d_in[1];
  const float* d_t    = (const float*)d_in[2];
  const float* h_t    = (const float*)d_in[3];
  const float* amax_t = (const float*)d_in[4];
  const float* Wu     = (const float*)d_in[5];
  const float* bu     = (const float*)d_in[6];
  const float* Wg     = (const float*)d_in[7];
  const float* bg     = (const float*)d_in[8];
  const float* Wa     = (const float*)d_in[9];
  const float* Wd     = (const float*)d_in[10];
  float* out = (float*)d_out;

  const size_t NEED = (size_t)1048576 + (size_t)16777216;  // wsB + wsA
  if (ws_size >= NEED) {
    _Float16* wsB = (_Float16*)d_ws;
    _Float16* wsA = (_Float16*)((char*)d_ws + 1048576);
    pack_w_frag<<<256, 256, 0, stream>>>(Wu, Wg, Wa, Wd, wsB);
    pack_a<<<4096, 256, 0, stream>>>(x_t, h_t, wsA);
    rwa_stream<<<1024, 256, 0, stream>>>(n_t, d_t, amax_t, bu, bg, wsA, wsB, out);
  } else {
    _Float16* wsB = (_Float16*)d_ws;
    pack_w_swz<<<256, 256, 0, stream>>>(Wu, Wg, Wa, Wd, wsB);
    rwa_lds<<<2048, 256, 0, stream>>>(x_t, n_t, d_t, h_t, amax_t, bu, bg, wsB, out);
  }
}